// Round 6
// baseline (1188.755 us; speedup 1.0000x reference)
//
#include <hip/hip_runtime.h>
#include <math.h>

// ---------------------------------------------------------------------------
// DTIModel (EGNN + protein head) forward.
// R5 (resubmit after infra timeout): edge/node MFMA kernels widened to 128
// rows/WG (et=4 -> 16 MFMA per K-step per wave, weight loads amortized 2x),
// v_cvt_pk_bf16_f32 for all bf16 packing, XCD-chunked block swizzle for the
// edge kernel, parallel scan, geom reduced to a 2-byte radial store per edge.
// ---------------------------------------------------------------------------

static constexpr int NN  = 65536;   // nodes
static constexpr int NE  = 262144;  // edges
static constexpr int NB  = 2048;    // graphs
static constexpr int NDF = 32;      // node feat in
static constexpr int HD  = 128;     // hidden
static constexpr int NL  = 4;       // egnn layers
static constexpr int PED = 1280;    // protein embed
static constexpr int PHD = 512;     // protein hidden
static constexpr int CHD = 512;     // combined hidden
static constexpr float EPSV = 1e-8f;

static constexpr int KK1 = 9;  // ceil(265/32) edge GEMM1
static constexpr int KK2 = 4;  // 128/32
static constexpr int KKN1 = 8; // 256/32 node GEMM1
static constexpr int KKP = 40; // 1280/32 prot
static constexpr int KKC = 20; // 640/32 comb1

static constexpr int ES = 36;  // f32 LDS row stride (emb_in)

typedef __attribute__((ext_vector_type(8))) short bf8_t;
typedef __attribute__((ext_vector_type(4))) float f4_t;

__device__ __forceinline__ float sigmoid_f(float x) {
  return __fdividef(1.0f, 1.0f + __expf(-x));
}
__device__ __forceinline__ float silu_f(float x) { return x * sigmoid_f(x); }

__device__ __forceinline__ ushort f2bf(float f) {  // RNE (setup kernels)
  unsigned u = __float_as_uint(f);
  u += 0x7FFFu + ((u >> 16) & 1u);
  return (ushort)(u >> 16);
}
__device__ __forceinline__ float bf2f(ushort h) {
  return __uint_as_float(((unsigned)h) << 16);
}
// packed RNE bf16x2 via HW instruction: low half <- a, high half <- b
__device__ __forceinline__ unsigned pk2bf(float a, float b) {
  unsigned r;
  asm("v_cvt_pk_bf16_f32 %0, %1, %2" : "=v"(r) : "v"(a), "v"(b));
  return r;
}

__device__ __forceinline__ void fma44(float (&acc)[4][4], const float4 a, const float4 w) {
  const float av[4] = {a.x, a.y, a.z, a.w};
  const float wv[4] = {w.x, w.y, w.z, w.w};
#pragma unroll
  for (int i = 0; i < 4; ++i)
#pragma unroll
    for (int j = 0; j < 4; ++j) acc[i][j] = fmaf(av[i], wv[j], acc[i][j]);
}

// --------------------------- CSR construction ------------------------------

__global__ void hist_kernel(const int* __restrict__ ei, int* __restrict__ deg) {
  const int e = blockIdx.x * 256 + threadIdx.x;
  if (e < NE) atomicAdd(&deg[ei[e]], 1);
}

// two-phase parallel exclusive scan of deg[NN] -> row_ptr[NN+1]
__global__ __launch_bounds__(256) void scan1_kernel(const int* __restrict__ deg,
                                                    int* __restrict__ cbase) {
  __shared__ int wsum[4];
  const int t = threadIdx.x;
  const int lane = t & 63, wave = t >> 6;
  int s = 0;
  const int4* p = (const int4*)deg + (size_t)t * 64;
#pragma unroll 8
  for (int j = 0; j < 64; ++j) {
    const int4 v = p[j];
    s += v.x + v.y + v.z + v.w;
  }
  int incl = s;
#pragma unroll
  for (int d = 1; d < 64; d <<= 1) {
    const int u = __shfl_up(incl, d, 64);
    if (lane >= d) incl += u;
  }
  if (lane == 63) wsum[wave] = incl;
  __syncthreads();
  int base = 0;
  for (int w2 = 0; w2 < wave; ++w2) base += wsum[w2];
  cbase[t] = base + incl - s;  // exclusive prefix of 256-chunk sums
}

__global__ __launch_bounds__(256) void scan2_kernel(const int* __restrict__ deg,
                                                    const int* __restrict__ cbase,
                                                    int* __restrict__ row_ptr) {
  __shared__ int wsum[4];
  const int b = blockIdx.x, t = threadIdx.x;
  const int lane = t & 63, wave = t >> 6;
  const int i = b * 256 + t;
  const int s = deg[i];
  int incl = s;
#pragma unroll
  for (int d = 1; d < 64; d <<= 1) {
    const int u = __shfl_up(incl, d, 64);
    if (lane >= d) incl += u;
  }
  if (lane == 63) wsum[wave] = incl;
  __syncthreads();
  int base = cbase[b];
  for (int w2 = 0; w2 < wave; ++w2) base += wsum[w2];
  row_ptr[i + 1] = base + incl;
  if (i == 0) row_ptr[0] = 0;
}

__global__ void fill_kernel(const int* __restrict__ ei, const int* __restrict__ row_ptr,
                            int* __restrict__ fill_pos, int* __restrict__ edge_ids) {
  const int e = blockIdx.x * 256 + threadIdx.x;
  if (e < NE) {
    const int n = ei[e];
    const int s = atomicAdd(&fill_pos[n], 1);
    edge_ids[row_ptr[n] + s] = e;
  }
}

// CSR-position arrays + constant part of the bf16 extra rows
__global__ void perm_kernel(const int* __restrict__ ei, const int* __restrict__ edge_ids,
                            const float* __restrict__ edge_attr,
                            int* __restrict__ rowp, int* __restrict__ colp,
                            ushort* __restrict__ extra) {
  const int i = blockIdx.x * 256 + threadIdx.x;
  if (i >= NE) return;
  const int e = edge_ids[i];
  rowp[i] = ei[e];
  colp[i] = ei[NE + e];
  const float4 a = *(const float4*)(edge_attr + (size_t)e * 8);
  const float4 b = *(const float4*)(edge_attr + (size_t)e * 8 + 4);
  ushort* dst = extra + (size_t)i * 32;
  *(uint4*)(dst) = make_uint4(pk2bf(0.0f, a.x), pk2bf(a.y, a.z),
                              pk2bf(a.w, b.x), pk2bf(b.y, b.z));
  *(uint4*)(dst + 8)  = make_uint4(pk2bf(b.w, 0.0f), 0, 0, 0);
  *(uint4*)(dst + 16) = make_uint4(0, 0, 0, 0);
  *(uint4*)(dst + 24) = make_uint4(0, 0, 0, 0);
}

__global__ void pos_copy_kernel(const float* __restrict__ pos, float* __restrict__ pc) {
  const int n = blockIdx.x * 256 + threadIdx.x;
  if (n < NN) {
    const float4 v = make_float4(pos[(size_t)n * 3 + 0], pos[(size_t)n * 3 + 1],
                                 pos[(size_t)n * 3 + 2], 0.0f);
    *(float4*)(pc + (size_t)n * 4) = v;
  }
}

// ------------------------- weight fragment packing -------------------------
// Wp[((kk*NTG + ntg)*64 + l)*8 + e] = bf16(W[k][n]), k = kk*32+(l>>4)*8+e,
// n = ntg*16+(l&15). Usable as either MFMA operand (A/B layouts symmetric).

__global__ __launch_bounds__(256) void packw_kernel(
    const float* __restrict__ W, ushort* __restrict__ Wp,
    int K, int N, int KK, size_t sW, size_t sWp) {
  const int layer = blockIdx.y;
  const int NTG = N >> 4;
  const int i = blockIdx.x * 256 + threadIdx.x;
  if (i >= KK * NTG * 64) return;
  const int l = i & 63;
  const int q = i >> 6;
  const int ntg = q % NTG;
  const int kk = q / NTG;
  const int k0 = kk * 32 + ((l >> 4) * 8);
  const int n = ntg * 16 + (l & 15);
  const float* w = W + layer * sW;
  unsigned ww[4];
#pragma unroll
  for (int p = 0; p < 4; ++p) {
    const int ka = k0 + p * 2, kb = ka + 1;
    const unsigned lo = (ka < K) ? f2bf(w[(size_t)ka * N + n]) : 0;
    const unsigned hi = (kb < K) ? f2bf(w[(size_t)kb * N + n]) : 0;
    ww[p] = lo | (hi << 16);
  }
  *(uint4*)(Wp + layer * sWp + (size_t)i * 8) = make_uint4(ww[0], ww[1], ww[2], ww[3]);
}

// f32 -> bf16 bulk convert
__global__ __launch_bounds__(256) void cvt_bf_kernel(const float* __restrict__ in,
                                                     ushort* __restrict__ out, int n) {
  const int i = blockIdx.x * 256 + threadIdx.x;
  if (i * 8 >= n) return;
  const float4 v0 = *(const float4*)(in + (size_t)i * 8);
  const float4 v1 = *(const float4*)(in + (size_t)i * 8 + 4);
  *(uint4*)(out + (size_t)i * 8) =
      make_uint4(pk2bf(v0.x, v0.y), pk2bf(v0.z, v0.w), pk2bf(v1.x, v1.y), pk2bf(v1.z, v1.w));
}

// ------------------------- per-layer edge geometry -------------------------
// only radial changes per layer: 2-byte store into extra[i*32], plus dnb.

__global__ __launch_bounds__(256) void geom_kernel(
    const float* __restrict__ pos_cur,
    const int* __restrict__ rowp, const int* __restrict__ colp,
    float* __restrict__ dnb, ushort* __restrict__ extra) {
  const int i = blockIdx.x * 256 + threadIdx.x;
  if (i >= NE) return;
  const int r = rowp[i], c = colp[i];
  const float4 pr = *(const float4*)(pos_cur + (size_t)r * 4);
  const float4 pc = *(const float4*)(pos_cur + (size_t)c * 4);
  const float dx = pr.x - pc.x, dy = pr.y - pc.y, dz = pr.z - pc.z;
  const float radial = dx * dx + dy * dy + dz * dz;
  const float inv = 1.0f / (sqrtf(radial) + EPSV);
  *(float4*)(dnb + (size_t)i * 4) = make_float4(dx * inv, dy * inv, dz * inv, 0.0f);
  extra[(size_t)i * 32] = f2bf(radial);
}

// ------------------------------- emb_in ------------------------------------

__global__ __launch_bounds__(256) void emb_in_kernel(
    const float* __restrict__ x, const float* __restrict__ W,
    const float* __restrict__ B, float* __restrict__ h, ushort* __restrict__ hbf) {
  __shared__ float xs[NDF * ES];
  const int t = threadIdx.x;
  const int n0 = blockIdx.x * 32;
  {
    const int r = t >> 3;
    const int kq = (t & 7) * 4;
    const float4 v = *(const float4*)(x + (size_t)(n0 + r) * NDF + kq);
    xs[(kq + 0) * ES + r] = v.x;
    xs[(kq + 1) * ES + r] = v.y;
    xs[(kq + 2) * ES + r] = v.z;
    xs[(kq + 3) * ES + r] = v.w;
  }
  __syncthreads();
  const int eg = t & 7, fg = t >> 3;
  float acc[4][4] = {};
  const float* wp = W + fg * 4;
#pragma unroll
  for (int k = 0; k < NDF; ++k) {
    const float4 a = *(const float4*)&xs[k * ES + eg * 4];
    const float4 w = *(const float4*)(wp + (size_t)k * HD);
    fma44(acc, a, w);
  }
  const float4 bv = *(const float4*)(B + fg * 4);
  const float bb[4] = {bv.x, bv.y, bv.z, bv.w};
#pragma unroll
  for (int i = 0; i < 4; ++i) {
    const float4 o = make_float4(acc[i][0] + bb[0], acc[i][1] + bb[1],
                                 acc[i][2] + bb[2], acc[i][3] + bb[3]);
    *(float4*)(h + (size_t)(n0 + eg * 4 + i) * HD + fg * 4) = o;
    *(uint2*)(hbf + (size_t)(n0 + eg * 4 + i) * HD + fg * 4) =
        make_uint2(pk2bf(o.x, o.y), pk2bf(o.z, o.w));
  }
}

// --------------------- transposed MFMA edge kernel -------------------------
// 128 edges x 128 feats per WG, 4 waves (wn: feat half, we: edge half);
// per wave 64 feats x 64 edges = 4(mt) x 4(et) fragments -> 16 MFMA/K-step.

__global__ __launch_bounds__(256) void edge_mfma_kernel(
    const ushort* __restrict__ hbf, const ushort* __restrict__ extra,
    const int* __restrict__ rowp, const int* __restrict__ colp,
    const float* __restrict__ dnb,
    const ushort* __restrict__ W1p, const float* __restrict__ B1,
    const ushort* __restrict__ W2p, const float* __restrict__ B2,
    const float* __restrict__ AW, const float* __restrict__ AB,
    const ushort* __restrict__ CW1p, const float* __restrict__ CB1,
    const float* __restrict__ CW2,
    ushort* __restrict__ m_bf, float* __restrict__ trans_out) {
  __shared__ ushort mtileT[128 * 128];  // [edge][feat^swz], 32 KB
  __shared__ int ridx[128], cidx[128];
  __shared__ float redbuf[2][128];
  __shared__ float gates[128];

  const int t = threadIdx.x;
  // XCD-chunked swizzle: 2048 blocks, 8 XCDs -> contiguous 256-block chunks
  const int bid = blockIdx.x;
  const int e0 = ((bid & 7) * (NE / 128 / 8) + (bid >> 3)) * 128;
  if (t < 128) {
    ridx[t] = rowp[e0 + t];
    cidx[t] = colp[e0 + t];
  }
  __syncthreads();

  const int w = t >> 6, l = t & 63;
  const int wn = w & 1, we = w >> 1;
  const int g = l >> 4, ln = l & 15;
  const int nb = wn * 64;  // feature base (M)
  const int eb = we * 64;  // edge base (N)

  int je[4], er[4], ec[4], swz[4];
#pragma unroll
  for (int et = 0; et < 4; ++et) {
    je[et] = eb + et * 16 + ln;
    er[et] = ridx[je[et]];
    ec[et] = cidx[je[et]];
    swz[et] = (je[et] & 7) << 3;
  }

  const f4_t zf = {0.0f, 0.0f, 0.0f, 0.0f};
  f4_t acc[4][4];
#pragma unroll
  for (int mt = 0; mt < 4; ++mt)
#pragma unroll
    for (int et = 0; et < 4; ++et) acc[mt][et] = zf;

  // ---- GEMM1: m1T[n][e] = sum_k W1[k][n] * e_in[e][k], K=288
#pragma unroll
  for (int kk = 0; kk < KK1; ++kk) {
    bf8_t aw[4], be[4];
#pragma unroll
    for (int mt = 0; mt < 4; ++mt)
      aw[mt] = *(const bf8_t*)(W1p + ((size_t)(kk * 8 + wn * 4 + mt) * 64 + l) * 8);
#pragma unroll
    for (int et = 0; et < 4; ++et) {
      if (kk < 8) {
        const int idx = (kk < 4) ? er[et] : ec[et];
        be[et] = *(const bf8_t*)(hbf + (size_t)idx * HD + (kk & 3) * 32 + g * 8);
      } else {
        be[et] = *(const bf8_t*)(extra + (size_t)(e0 + je[et]) * 32 + g * 8);
      }
    }
#pragma unroll
    for (int mt = 0; mt < 4; ++mt)
#pragma unroll
      for (int et = 0; et < 4; ++et)
        acc[mt][et] = __builtin_amdgcn_mfma_f32_16x16x32_bf16(aw[mt], be[et], acc[mt][et], 0, 0, 0);
  }

  // m1 = silu(acc + b1) -> LDS (cvt_pk + ds_write_b64)
#pragma unroll
  for (int mt = 0; mt < 4; ++mt) {
    const int n0 = nb + mt * 16 + g * 4;
    const float4 bv = *(const float4*)(B1 + n0);
#pragma unroll
    for (int et = 0; et < 4; ++et) {
      const unsigned lo = pk2bf(silu_f(acc[mt][et][0] + bv.x), silu_f(acc[mt][et][1] + bv.y));
      const unsigned hi = pk2bf(silu_f(acc[mt][et][2] + bv.z), silu_f(acc[mt][et][3] + bv.w));
      *(uint2*)&mtileT[je[et] * HD + (n0 ^ swz[et])] = make_uint2(lo, hi);
    }
  }
  __syncthreads();

  // ---- GEMM2: m2T = W2T @ m1T, K=128 (+ attention gate)
  f4_t acc2[4][4];
#pragma unroll
  for (int mt = 0; mt < 4; ++mt)
#pragma unroll
    for (int et = 0; et < 4; ++et) acc2[mt][et] = zf;
#pragma unroll
  for (int kk = 0; kk < KK2; ++kk) {
    bf8_t aw[4], be[4];
#pragma unroll
    for (int mt = 0; mt < 4; ++mt)
      aw[mt] = *(const bf8_t*)(W2p + ((size_t)(kk * 8 + wn * 4 + mt) * 64 + l) * 8);
    const int nk = kk * 32 + g * 8;
#pragma unroll
    for (int et = 0; et < 4; ++et)
      be[et] = *(const bf8_t*)&mtileT[je[et] * HD + (nk ^ swz[et])];
#pragma unroll
    for (int mt = 0; mt < 4; ++mt)
#pragma unroll
      for (int et = 0; et < 4; ++et)
        acc2[mt][et] = __builtin_amdgcn_mfma_f32_16x16x32_bf16(aw[mt], be[et], acc2[mt][et], 0, 0, 0);
  }

  // attention gate: p[e] = sum_n silu(m2) * aw[n]
  {
    float p[4] = {0.0f, 0.0f, 0.0f, 0.0f};
#pragma unroll
    for (int mt = 0; mt < 4; ++mt) {
      const int n0 = nb + mt * 16 + g * 4;
      const float4 bv = *(const float4*)(B2 + n0);
      const float4 av = *(const float4*)(AW + n0);
      const float bb[4] = {bv.x, bv.y, bv.z, bv.w};
      const float aa[4] = {av.x, av.y, av.z, av.w};
#pragma unroll
      for (int et = 0; et < 4; ++et)
#pragma unroll
        for (int r = 0; r < 4; ++r)
          p[et] = fmaf(silu_f(acc2[mt][et][r] + bb[r]), aa[r], p[et]);
    }
#pragma unroll
    for (int et = 0; et < 4; ++et) {
      p[et] += __shfl_xor(p[et], 16, 64);
      p[et] += __shfl_xor(p[et], 32, 64);
    }
    if (l < 16) {
#pragma unroll
      for (int et = 0; et < 4; ++et) redbuf[wn][eb + et * 16 + l] = p[et];
    }
  }
  __syncthreads();
  if (t < 128) gates[t] = sigmoid_f(redbuf[0][t] + redbuf[1][t] + AB[0]);
  __syncthreads();

  // gated m -> LDS (recompute silu from held acc2; saves 64 VGPRs)
#pragma unroll
  for (int mt = 0; mt < 4; ++mt) {
    const int n0 = nb + mt * 16 + g * 4;
    const float4 bv = *(const float4*)(B2 + n0);
#pragma unroll
    for (int et = 0; et < 4; ++et) {
      const float gr = gates[je[et]];
      const unsigned lo = pk2bf(silu_f(acc2[mt][et][0] + bv.x) * gr,
                                silu_f(acc2[mt][et][1] + bv.y) * gr);
      const unsigned hi = pk2bf(silu_f(acc2[mt][et][2] + bv.z) * gr,
                                silu_f(acc2[mt][et][3] + bv.w) * gr);
      *(uint2*)&mtileT[je[et] * HD + (n0 ^ swz[et])] = make_uint2(lo, hi);
    }
  }
  __syncthreads();

  // ---- GEMM3: t2T = CW1T @ mT, K=128; coord scalar = tanh(t2 . cw2)
  f4_t acc3[4][4];
#pragma unroll
  for (int mt = 0; mt < 4; ++mt)
#pragma unroll
    for (int et = 0; et < 4; ++et) acc3[mt][et] = zf;
#pragma unroll
  for (int kk = 0; kk < KK2; ++kk) {
    bf8_t aw[4], be[4];
#pragma unroll
    for (int mt = 0; mt < 4; ++mt)
      aw[mt] = *(const bf8_t*)(CW1p + ((size_t)(kk * 8 + wn * 4 + mt) * 64 + l) * 8);
    const int nk = kk * 32 + g * 8;
#pragma unroll
    for (int et = 0; et < 4; ++et)
      be[et] = *(const bf8_t*)&mtileT[je[et] * HD + (nk ^ swz[et])];
#pragma unroll
    for (int mt = 0; mt < 4; ++mt)
#pragma unroll
      for (int et = 0; et < 4; ++et)
        acc3[mt][et] = __builtin_amdgcn_mfma_f32_16x16x32_bf16(aw[mt], be[et], acc3[mt][et], 0, 0, 0);
  }
  {
    float q[4] = {0.0f, 0.0f, 0.0f, 0.0f};
#pragma unroll
    for (int mt = 0; mt < 4; ++mt) {
      const int n0 = nb + mt * 16 + g * 4;
      const float4 bv = *(const float4*)(CB1 + n0);
      const float4 cv = *(const float4*)(CW2 + n0);
      const float bb[4] = {bv.x, bv.y, bv.z, bv.w};
      const float cc[4] = {cv.x, cv.y, cv.z, cv.w};
#pragma unroll
      for (int et = 0; et < 4; ++et)
#pragma unroll
        for (int r = 0; r < 4; ++r)
          q[et] = fmaf(silu_f(acc3[mt][et][r] + bb[r]), cc[r], q[et]);
    }
#pragma unroll
    for (int et = 0; et < 4; ++et) {
      q[et] += __shfl_xor(q[et], 16, 64);
      q[et] += __shfl_xor(q[et], 32, 64);
    }
    if (l < 16) {
#pragma unroll
      for (int et = 0; et < 4; ++et) redbuf[wn][eb + et * 16 + l] = q[et];
    }
  }
  __syncthreads();
  if (t < 128) {
    const float s = tanhf(redbuf[0][t] + redbuf[1][t]);
    const f4_t dn = *(const f4_t*)(dnb + (size_t)(e0 + t) * 4);
    const f4_t tr = dn * s;
    *(f4_t*)(trans_out + (size_t)(e0 + t) * 4) = tr;
  }

  // bulk copy gated-m LDS tile -> global m_bf (de-swizzle, coalesced)
#pragma unroll
  for (int it = 0; it < 8; ++it) {
    const int i = it * 256 + t;
    const int row = i >> 4;
    const int c8 = (i & 15) * 8;
    const uint4 v = *(const uint4*)&mtileT[row * HD + (c8 ^ ((row & 7) << 3))];
    *(uint4*)(m_bf + (size_t)(e0 + row) * HD + c8) = v;
  }
}

// ------------------------ gather (segment sums) ----------------------------
// CSR-ordered m rows: fully sequential stream. One wave per node.

__global__ __launch_bounds__(256) void gather_kernel(
    const ushort* __restrict__ m_bf, const float* __restrict__ trans,
    const int* __restrict__ row_ptr,
    ushort* __restrict__ agg_bf, float* __restrict__ pos_cur) {
  const int t = threadIdx.x;
  const int wave = t >> 6, lane = t & 63;
  const int n = blockIdx.x * 4 + wave;
  const int s = row_ptr[n], e_end = row_ptr[n + 1];
  float a0 = 0.0f, a1 = 0.0f, ta = 0.0f;
  for (int i = s; i < e_end; ++i) {
    const ushort2 v = *(const ushort2*)(m_bf + (size_t)i * HD + lane * 2);
    a0 += bf2f(v.x);
    a1 += bf2f(v.y);
    if (lane < 4) ta += trans[(size_t)i * 4 + lane];
  }
  *(unsigned*)(agg_bf + (size_t)n * HD + lane * 2) = pk2bf(a0, a1);
  if (lane < 3) {
    const int dg = e_end - s;
    pos_cur[(size_t)n * 4 + lane] += ta / (float)(dg > 0 ? dg : 1);
  }
}

// --------------------- transposed MFMA node kernel -------------------------
// 128 nodes x 128 feats per WG; sequential activation reads.

__global__ __launch_bounds__(256) void node_mfma_kernel(
    float* __restrict__ h, const ushort* __restrict__ hbf,
    const ushort* __restrict__ agg_bf,
    const ushort* __restrict__ W1p, const float* __restrict__ B1,
    const ushort* __restrict__ W2p, const float* __restrict__ B2,
    ushort* __restrict__ hbf_out) {
  __shared__ ushort mtileT[128 * 128];
  const int t = threadIdx.x;
  const int n0blk = blockIdx.x * 128;
  const int w = t >> 6, l = t & 63;
  const int wn = w & 1, we = w >> 1;
  const int g = l >> 4, ln = l & 15;
  const int nb = wn * 64;
  const int eb = we * 64;

  int jn[4], swz[4];
#pragma unroll
  for (int et = 0; et < 4; ++et) {
    jn[et] = eb + et * 16 + ln;
    swz[et] = (jn[et] & 7) << 3;
  }

  const f4_t zf = {0.0f, 0.0f, 0.0f, 0.0f};
  f4_t acc[4][4];
#pragma unroll
  for (int mt = 0; mt < 4; ++mt)
#pragma unroll
    for (int et = 0; et < 4; ++et) acc[mt][et] = zf;

  // GEMM1: K=256 ([h|agg])
#pragma unroll
  for (int kk = 0; kk < KKN1; ++kk) {
    bf8_t aw[4], be[4];
#pragma unroll
    for (int mt = 0; mt < 4; ++mt)
      aw[mt] = *(const bf8_t*)(W1p + ((size_t)(kk * 8 + wn * 4 + mt) * 64 + l) * 8);
#pragma unroll
    for (int et = 0; et < 4; ++et) {
      const size_t base = (size_t)(n0blk + jn[et]) * HD + (kk & 3) * 32 + g * 8;
      be[et] = (kk < 4) ? *(const bf8_t*)(hbf + base) : *(const bf8_t*)(agg_bf + base);
    }
#pragma unroll
    for (int mt = 0; mt < 4; ++mt)
#pragma unroll
      for (int et = 0; et < 4; ++et)
        acc[mt][et] = __builtin_amdgcn_mfma_f32_16x16x32_bf16(aw[mt], be[et], acc[mt][et], 0, 0, 0);
  }
#pragma unroll
  for (int mt = 0; mt < 4; ++mt) {
    const int n0 = nb + mt * 16 + g * 4;
    const float4 bv = *(const float4*)(B1 + n0);
#pragma unroll
    for (int et = 0; et < 4; ++et) {
      const unsigned lo = pk2bf(silu_f(acc[mt][et][0] + bv.x), silu_f(acc[mt][et][1] + bv.y));
      const unsigned hi = pk2bf(silu_f(acc[mt][et][2] + bv.z), silu_f(acc[mt][et][3] + bv.w));
      *(uint2*)&mtileT[jn[et] * HD + (n0 ^ swz[et])] = make_uint2(lo, hi);
    }
  }
  __syncthreads();

  // GEMM2: K=128; h += out + b2
  f4_t acc2[4][4];
#pragma unroll
  for (int mt = 0; mt < 4; ++mt)
#pragma unroll
    for (int et = 0; et < 4; ++et) acc2[mt][et] = zf;
#pragma unroll
  for (int kk = 0; kk < KK2; ++kk) {
    bf8_t aw[4], be[4];
#pragma unroll
    for (int mt = 0; mt < 4; ++mt)
      aw[mt] = *(const bf8_t*)(W2p + ((size_t)(kk * 8 + wn * 4 + mt) * 64 + l) * 8);
    const int nk = kk * 32 + g * 8;
#pragma unroll
    for (int et = 0; et < 4; ++et)
      be[et] = *(const bf8_t*)&mtileT[jn[et] * HD + (nk ^ swz[et])];
#pragma unroll
    for (int mt = 0; mt < 4; ++mt)
#pragma unroll
      for (int et = 0; et < 4; ++et)
        acc2[mt][et] = __builtin_amdgcn_mfma_f32_16x16x32_bf16(aw[mt], be[et], acc2[mt][et], 0, 0, 0);
  }
#pragma unroll
  for (int mt = 0; mt < 4; ++mt) {
    const int n0 = nb + mt * 16 + g * 4;
    const float4 bv = *(const float4*)(B2 + n0);
#pragma unroll
    for (int et = 0; et < 4; ++et) {
      float* hp = h + (size_t)(n0blk + jn[et]) * HD + n0;
      const float4 old = *(const float4*)hp;
      float4 o;
      o.x = old.x + acc2[mt][et][0] + bv.x;
      o.y = old.y + acc2[mt][et][1] + bv.y;
      o.z = old.z + acc2[mt][et][2] + bv.z;
      o.w = old.w + acc2[mt][et][3] + bv.w;
      *(float4*)hp = o;
      *(uint2*)(hbf_out + (size_t)(n0blk + jn[et]) * HD + n0) =
          make_uint2(pk2bf(o.x, o.y), pk2bf(o.z, o.w));
    }
  }
}

// ------------------------- generic MFMA head GEMM --------------------------

__global__ __launch_bounds__(256) void gemm_head_kernel(
    const ushort* __restrict__ A, const ushort* __restrict__ Wp,
    const float* __restrict__ bias, ushort* __restrict__ out,
    int lda, int KK, int NTG, int ldo, int col_off) {
  const int t = threadIdx.x;
  const int rb = blockIdx.x * 64;
  const int cb = blockIdx.y * 128;
  const int w = t >> 6, l = t & 63;
  const int wr = w >> 1, wc = w & 1;
  const int g = l >> 4, ln = l & 15;
  const int row0 = wr * 32;
  int rowA[2];
#pragma unroll
  for (int mt = 0; mt < 2; ++mt) rowA[mt] = row0 + mt * 16 + ln;

  const f4_t zf = {0.0f, 0.0f, 0.0f, 0.0f};
  f4_t acc[2][4];
#pragma unroll
  for (int mt = 0; mt < 2; ++mt)
#pragma unroll
    for (int nt = 0; nt < 4; ++nt) acc[mt][nt] = zf;

  const int ntg0 = (cb >> 4) + wc * 4;
  for (int kk = 0; kk < KK; ++kk) {
    bf8_t a[2], b[4];
#pragma unroll
    for (int mt = 0; mt < 2; ++mt)
      a[mt] = *(const bf8_t*)(A + (size_t)(rb + rowA[mt]) * lda + kk * 32 + g * 8);
#pragma unroll
    for (int nt = 0; nt < 4; ++nt)
      b[nt] = *(const bf8_t*)(Wp + ((size_t)(kk * NTG + ntg0 + nt) * 64 + l) * 8);
#pragma unroll
    for (int mt = 0; mt < 2; ++mt)
#pragma unroll
      for (int nt = 0; nt < 4; ++nt)
        acc[mt][nt] = __builtin_amdgcn_mfma_f32_16x16x32_bf16(a[mt], b[nt], acc[mt][nt], 0, 0, 0);
  }
  {
    float bn[4];
#pragma unroll
    for (int nt = 0; nt < 4; ++nt) bn[nt] = bias[cb + wc * 64 + nt * 16 + ln];
#pragma unroll
    for (int mt = 0; mt < 2; ++mt)
#pragma unroll
      for (int nt = 0; nt < 4; ++nt) {
        const int col = cb + wc * 64 + nt * 16 + ln;
#pragma unroll
        for (int r = 0; r < 4; ++r) {
          const int row = row0 + mt * 16 + g * 4 + r;
          const float v = fmaxf(acc[mt][nt][r] + bn[nt], 0.0f);
          out[(size_t)(rb + row) * ldo + col_off + col] = f2bf(v);
        }
      }
  }
}

// ------------------------------ heads --------------------------------------

__global__ __launch_bounds__(128) void pool_kernel(
    const float* __restrict__ h, const float* __restrict__ W,
    const float* __restrict__ B, ushort* __restrict__ c_in) {
  __shared__ float mh[HD];
  const int g = blockIdx.x, t = threadIdx.x;
  float s = 0.0f;
#pragma unroll 4
  for (int n = 0; n < 32; ++n) s += h[((size_t)g * 32 + n) * HD + t];
  mh[t] = s * (1.0f / 32.0f);
  __syncthreads();
  float acc = B[t];
#pragma unroll 4
  for (int k = 0; k < HD; ++k) acc = fmaf(mh[k], W[(size_t)k * HD + t], acc);
  c_in[(size_t)g * (HD + PHD) + t] = f2bf(acc);
}

__global__ __launch_bounds__(256) void logits_kernel(
    const ushort* __restrict__ c, const float* __restrict__ w2,
    const float* __restrict__ b2, float* __restrict__ out) {
  const int t = threadIdx.x;
  const int wave = t >> 6, lane = t & 63;
  const int r = blockIdx.x * 4 + wave;
  const ushort* cp = c + (size_t)r * CHD + lane * 8;
  const float* wp = w2 + lane * 8;
  float s = 0.0f;
#pragma unroll
  for (int j = 0; j < 8; ++j) s = fmaf(bf2f(cp[j]), wp[j], s);
#pragma unroll
  for (int off = 32; off > 0; off >>= 1) s += __shfl_down(s, off, 64);
  if (lane == 0) {
    out[r] = s + b2[0];
    out[NB + r] = 0.0f;
  }
}

// ------------------------------ launch -------------------------------------

extern "C" void kernel_launch(void* const* d_in, const int* in_sizes, int n_in,
                              void* d_out, int out_size, void* d_ws, size_t ws_size,
                              hipStream_t stream) {
  const float* x          = (const float*)d_in[0];
  const float* pos        = (const float*)d_in[1];
  const float* edge_attr  = (const float*)d_in[2];
  const float* pe         = (const float*)d_in[3];
  const int*   edge_index = (const int*)d_in[4];
  const float* emb_in_w   = (const float*)d_in[6];
  const float* emb_in_b   = (const float*)d_in[7];
  const float* emb_out_w  = (const float*)d_in[8];
  const float* emb_out_b  = (const float*)d_in[9];
  const float* edge_w1    = (const float*)d_in[10];
  const float* edge_b1    = (const float*)d_in[11];
  const float* edge_w2    = (const float*)d_in[12];
  const float* edge_b2    = (const float*)d_in[13];
  const float* att_w      = (const float*)d_in[14];
  const float* att_b      = (const float*)d_in[15];
  const float* coord_w1   = (const float*)d_in[16];
  const float* coord_b1   = (const float*)d_in[17];
  const float* coord_w2   = (const float*)d_in[18];
  const float* node_w1    = (const float*)d_in[19];
  const float* node_b1    = (const float*)d_in[20];
  const float* node_w2    = (const float*)d_in[21];
  const float* node_b2    = (const float*)d_in[22];
  const float* prot_w     = (const float*)d_in[23];
  const float* prot_b     = (const float*)d_in[24];
  const float* comb_w1    = (const float*)d_in[25];
  const float* comb_b1    = (const float*)d_in[26];
  const float* comb_w2    = (const float*)d_in[27];
  const float* comb_b2    = (const float*)d_in[28];
  float* out = (float*)d_out;
  (void)in_sizes; (void)n_in; (void)out_size; (void)ws_size;

  char* ws = (char*)d_ws;
  size_t off = 0;
  auto carve = [&](size_t bytes) -> void* {
    void* p = ws + off;
    off += (bytes + 255) & ~(size_t)255;
    return p;
  };
  float*  h       = (float*)carve((size_t)NN * HD * 4);
  ushort* h_bf    = (ushort*)carve((size_t)NN * HD * 2);
  ushort* agg_bf  = (ushort*)carve((size_t)NN * HD * 2);
  ushort* m_bf    = (ushort*)carve((size_t)NE * HD * 2);
  float*  trans   = (float*)carve((size_t)NE * 4 * 4);
  float*  dnb     = (float*)carve((size_t)NE * 4 * 4);
  ushort* extra   = (ushort*)carve((size_t)NE * 32 * 2);
  float*  pos_cur = (float*)carve((size_t)NN * 4 * 4);
  ushort* pe_bf   = (ushort*)carve((size_t)NB * PED * 2);
  ushort* c_in    = (ushort*)carve((size_t)NB * (HD + PHD) * 2);
  ushort* c1      = (ushort*)carve((size_t)NB * CHD * 2);
  const size_t sW1p  = (size_t)KK1 * 8 * 64 * 8;
  const size_t sW2p  = (size_t)KK2 * 8 * 64 * 8;
  const size_t sNW1p = (size_t)KKN1 * 8 * 64 * 8;
  const size_t sPWp  = (size_t)KKP * 32 * 64 * 8;
  const size_t sCWp  = (size_t)KKC * 32 * 64 * 8;
  ushort* W1p     = (ushort*)carve(sW1p * NL * 2);
  ushort* W2p     = (ushort*)carve(sW2p * NL * 2);
  ushort* CW1p    = (ushort*)carve(sW2p * NL * 2);
  ushort* NW1p    = (ushort*)carve(sNW1p * NL * 2);
  ushort* NW2p    = (ushort*)carve(sW2p * NL * 2);
  ushort* PWp     = (ushort*)carve(sPWp * 2);
  ushort* CWp     = (ushort*)carve(sCWp * 2);
  int* deg        = (int*)carve((size_t)NN * 4);
  int* row_ptr    = (int*)carve((size_t)(NN + 1) * 4);
  int* fill_pos   = (int*)carve((size_t)NN * 4);
  int* edge_ids   = (int*)carve((size_t)NE * 4);
  int* rowp       = (int*)carve((size_t)NE * 4);
  int* colp       = (int*)carve((size_t)NE * 4);
  int* cbase      = (int*)carve((size_t)256 * 4);

  hipMemsetAsync(deg, 0, (size_t)NN * 4, stream);
  hipMemsetAsync(fill_pos, 0, (size_t)NN * 4, stream);

  pos_copy_kernel<<<NN / 256, 256, 0, stream>>>(pos, pos_cur);
  hist_kernel<<<NE / 256, 256, 0, stream>>>(edge_index, deg);
  scan1_kernel<<<1, 256, 0, stream>>>(deg, cbase);
  scan2_kernel<<<NN / 256, 256, 0, stream>>>(deg, cbase, row_ptr);
  fill_kernel<<<NE / 256, 256, 0, stream>>>(edge_index, row_ptr, fill_pos, edge_ids);
  perm_kernel<<<NE / 256, 256, 0, stream>>>(edge_index, edge_ids, edge_attr,
                                            rowp, colp, extra);

  packw_kernel<<<dim3(18, NL), 256, 0, stream>>>(edge_w1, W1p, 265, HD, KK1,
                                                 (size_t)265 * HD, sW1p);
  packw_kernel<<<dim3(8, NL), 256, 0, stream>>>(edge_w2, W2p, HD, HD, KK2,
                                                (size_t)HD * HD, sW2p);
  packw_kernel<<<dim3(8, NL), 256, 0, stream>>>(coord_w1, CW1p, HD, HD, KK2,
                                                (size_t)HD * HD, sW2p);
  packw_kernel<<<dim3(16, NL), 256, 0, stream>>>(node_w1, NW1p, 2 * HD, HD, KKN1,
                                                 (size_t)2 * HD * HD, sNW1p);
  packw_kernel<<<dim3(8, NL), 256, 0, stream>>>(node_w2, NW2p, HD, HD, KK2,
                                                (size_t)HD * HD, sW2p);
  packw_kernel<<<dim3(320, 1), 256, 0, stream>>>(prot_w, PWp, PED, PHD, KKP, 0, 0);
  packw_kernel<<<dim3(160, 1), 256, 0, stream>>>(comb_w1, CWp, HD + PHD, CHD, KKC, 0, 0);

  cvt_bf_kernel<<<NB * PED / (256 * 8), 256, 0, stream>>>(pe, pe_bf, NB * PED);

  emb_in_kernel<<<NN / 32, 256, 0, stream>>>(x, emb_in_w, emb_in_b, h, h_bf);

  for (int l = 0; l < NL; ++l) {
    geom_kernel<<<NE / 256, 256, 0, stream>>>(pos_cur, rowp, colp, dnb, extra);
    edge_mfma_kernel<<<NE / 128, 256, 0, stream>>>(
        h_bf, extra, rowp, colp, dnb,
        W1p + (size_t)l * sW1p, edge_b1 + (size_t)l * HD,
        W2p + (size_t)l * sW2p, edge_b2 + (size_t)l * HD,
        att_w + (size_t)l * HD, att_b + l,
        CW1p + (size_t)l * sW2p, coord_b1 + (size_t)l * HD,
        coord_w2 + (size_t)l * HD,
        m_bf, trans);
    gather_kernel<<<NN / 4, 256, 0, stream>>>(m_bf, trans, row_ptr, agg_bf, pos_cur);
    node_mfma_kernel<<<NN / 128, 256, 0, stream>>>(
        h, h_bf, agg_bf,
        NW1p + (size_t)l * sNW1p, node_b1 + (size_t)l * HD,
        NW2p + (size_t)l * sW2p, node_b2 + (size_t)l * HD, h_bf);
  }

  pool_kernel<<<NB, 128, 0, stream>>>(h, emb_out_w, emb_out_b, c_in);
  gemm_head_kernel<<<dim3(NB / 64, PHD / 128), 256, 0, stream>>>(
      pe_bf, PWp, prot_b, c_in, PED, KKP, PHD / 16, HD + PHD, HD);
  gemm_head_kernel<<<dim3(NB / 64, CHD / 128), 256, 0, stream>>>(
      c_in, CWp, comb_b1, c1, HD + PHD, KKC, CHD / 16, CHD, 0);
  logits_kernel<<<NB / 4, 256, 0, stream>>>(c1, comb_w2, comb_b2, out);
}

// Round 8
// 966.358 us; speedup vs baseline: 1.2301x; 1.2301x over previous
//
#include <hip/hip_runtime.h>
#include <math.h>

// ---------------------------------------------------------------------------
// DTIModel (EGNN + protein head) forward.
// R7 (resubmit after infra timeout): revert R5's tile widening (occupancy
// collapse 30->11% cost +50% dur). R4 tile geometry (64 edges/WG, et=2,
// ~72 VGPR, 16KB mtile) + the orthogonal R5 wins: v_cvt_pk_bf16_f32 packing,
// parallel scan, slim geom, perm pre-packed extra, XCD-chunked edge swizzle.
// ---------------------------------------------------------------------------

static constexpr int NN  = 65536;   // nodes
static constexpr int NE  = 262144;  // edges
static constexpr int NB  = 2048;    // graphs
static constexpr int NDF = 32;      // node feat in
static constexpr int HD  = 128;     // hidden
static constexpr int NL  = 4;       // egnn layers
static constexpr int PED = 1280;    // protein embed
static constexpr int PHD = 512;     // protein hidden
static constexpr int CHD = 512;     // combined hidden
static constexpr float EPSV = 1e-8f;

static constexpr int KK1 = 9;  // ceil(265/32) edge GEMM1
static constexpr int KK2 = 4;  // 128/32
static constexpr int KKN1 = 8; // 256/32 node GEMM1
static constexpr int KKP = 40; // 1280/32 prot
static constexpr int KKC = 20; // 640/32 comb1

static constexpr int ES = 36;  // f32 LDS row stride (emb_in)

typedef __attribute__((ext_vector_type(8))) short bf8_t;
typedef __attribute__((ext_vector_type(4))) float f4_t;

__device__ __forceinline__ float sigmoid_f(float x) {
  return __fdividef(1.0f, 1.0f + __expf(-x));
}
__device__ __forceinline__ float silu_f(float x) { return x * sigmoid_f(x); }

__device__ __forceinline__ ushort f2bf(float f) {  // RNE (setup kernels)
  unsigned u = __float_as_uint(f);
  u += 0x7FFFu + ((u >> 16) & 1u);
  return (ushort)(u >> 16);
}
__device__ __forceinline__ float bf2f(ushort h) {
  return __uint_as_float(((unsigned)h) << 16);
}
// packed RNE bf16x2 via HW instruction: low half <- a, high half <- b
__device__ __forceinline__ unsigned pk2bf(float a, float b) {
  unsigned r;
  asm("v_cvt_pk_bf16_f32 %0, %1, %2" : "=v"(r) : "v"(a), "v"(b));
  return r;
}

__device__ __forceinline__ void fma44(float (&acc)[4][4], const float4 a, const float4 w) {
  const float av[4] = {a.x, a.y, a.z, a.w};
  const float wv[4] = {w.x, w.y, w.z, w.w};
#pragma unroll
  for (int i = 0; i < 4; ++i)
#pragma unroll
    for (int j = 0; j < 4; ++j) acc[i][j] = fmaf(av[i], wv[j], acc[i][j]);
}

// --------------------------- CSR construction ------------------------------

__global__ void hist_kernel(const int* __restrict__ ei, int* __restrict__ deg) {
  const int e = blockIdx.x * 256 + threadIdx.x;
  if (e < NE) atomicAdd(&deg[ei[e]], 1);
}

// two-phase parallel exclusive scan of deg[NN] -> row_ptr[NN+1]
__global__ __launch_bounds__(256) void scan1_kernel(const int* __restrict__ deg,
                                                    int* __restrict__ cbase) {
  __shared__ int wsum[4];
  const int t = threadIdx.x;
  const int lane = t & 63, wave = t >> 6;
  int s = 0;
  const int4* p = (const int4*)deg + (size_t)t * 64;
#pragma unroll 8
  for (int j = 0; j < 64; ++j) {
    const int4 v = p[j];
    s += v.x + v.y + v.z + v.w;
  }
  int incl = s;
#pragma unroll
  for (int d = 1; d < 64; d <<= 1) {
    const int u = __shfl_up(incl, d, 64);
    if (lane >= d) incl += u;
  }
  if (lane == 63) wsum[wave] = incl;
  __syncthreads();
  int base = 0;
  for (int w2 = 0; w2 < wave; ++w2) base += wsum[w2];
  cbase[t] = base + incl - s;  // exclusive prefix of 256-chunk sums
}

__global__ __launch_bounds__(256) void scan2_kernel(const int* __restrict__ deg,
                                                    const int* __restrict__ cbase,
                                                    int* __restrict__ row_ptr) {
  __shared__ int wsum[4];
  const int b = blockIdx.x, t = threadIdx.x;
  const int lane = t & 63, wave = t >> 6;
  const int i = b * 256 + t;
  const int s = deg[i];
  int incl = s;
#pragma unroll
  for (int d = 1; d < 64; d <<= 1) {
    const int u = __shfl_up(incl, d, 64);
    if (lane >= d) incl += u;
  }
  if (lane == 63) wsum[wave] = incl;
  __syncthreads();
  int base = cbase[b];
  for (int w2 = 0; w2 < wave; ++w2) base += wsum[w2];
  row_ptr[i + 1] = base + incl;
  if (i == 0) row_ptr[0] = 0;
}

__global__ void fill_kernel(const int* __restrict__ ei, const int* __restrict__ row_ptr,
                            int* __restrict__ fill_pos, int* __restrict__ edge_ids) {
  const int e = blockIdx.x * 256 + threadIdx.x;
  if (e < NE) {
    const int n = ei[e];
    const int s = atomicAdd(&fill_pos[n], 1);
    edge_ids[row_ptr[n] + s] = e;
  }
}

// CSR-position arrays + constant part of the bf16 extra rows
__global__ void perm_kernel(const int* __restrict__ ei, const int* __restrict__ edge_ids,
                            const float* __restrict__ edge_attr,
                            int* __restrict__ rowp, int* __restrict__ colp,
                            ushort* __restrict__ extra) {
  const int i = blockIdx.x * 256 + threadIdx.x;
  if (i >= NE) return;
  const int e = edge_ids[i];
  rowp[i] = ei[e];
  colp[i] = ei[NE + e];
  const float4 a = *(const float4*)(edge_attr + (size_t)e * 8);
  const float4 b = *(const float4*)(edge_attr + (size_t)e * 8 + 4);
  ushort* dst = extra + (size_t)i * 32;
  *(uint4*)(dst) = make_uint4(pk2bf(0.0f, a.x), pk2bf(a.y, a.z),
                              pk2bf(a.w, b.x), pk2bf(b.y, b.z));
  *(uint4*)(dst + 8)  = make_uint4(pk2bf(b.w, 0.0f), 0, 0, 0);
  *(uint4*)(dst + 16) = make_uint4(0, 0, 0, 0);
  *(uint4*)(dst + 24) = make_uint4(0, 0, 0, 0);
}

__global__ void pos_copy_kernel(const float* __restrict__ pos, float* __restrict__ pc) {
  const int n = blockIdx.x * 256 + threadIdx.x;
  if (n < NN) {
    const float4 v = make_float4(pos[(size_t)n * 3 + 0], pos[(size_t)n * 3 + 1],
                                 pos[(size_t)n * 3 + 2], 0.0f);
    *(float4*)(pc + (size_t)n * 4) = v;
  }
}

// ------------------------- weight fragment packing -------------------------
// Wp[((kk*NTG + ntg)*64 + l)*8 + e] = bf16(W[k][n]), k = kk*32+(l>>4)*8+e,
// n = ntg*16+(l&15). Usable as either MFMA operand (A/B layouts symmetric).

__global__ __launch_bounds__(256) void packw_kernel(
    const float* __restrict__ W, ushort* __restrict__ Wp,
    int K, int N, int KK, size_t sW, size_t sWp) {
  const int layer = blockIdx.y;
  const int NTG = N >> 4;
  const int i = blockIdx.x * 256 + threadIdx.x;
  if (i >= KK * NTG * 64) return;
  const int l = i & 63;
  const int q = i >> 6;
  const int ntg = q % NTG;
  const int kk = q / NTG;
  const int k0 = kk * 32 + ((l >> 4) * 8);
  const int n = ntg * 16 + (l & 15);
  const float* w = W + layer * sW;
  unsigned ww[4];
#pragma unroll
  for (int p = 0; p < 4; ++p) {
    const int ka = k0 + p * 2, kb = ka + 1;
    const unsigned lo = (ka < K) ? f2bf(w[(size_t)ka * N + n]) : 0;
    const unsigned hi = (kb < K) ? f2bf(w[(size_t)kb * N + n]) : 0;
    ww[p] = lo | (hi << 16);
  }
  *(uint4*)(Wp + layer * sWp + (size_t)i * 8) = make_uint4(ww[0], ww[1], ww[2], ww[3]);
}

// f32 -> bf16 bulk convert
__global__ __launch_bounds__(256) void cvt_bf_kernel(const float* __restrict__ in,
                                                     ushort* __restrict__ out, int n) {
  const int i = blockIdx.x * 256 + threadIdx.x;
  if (i * 8 >= n) return;
  const float4 v0 = *(const float4*)(in + (size_t)i * 8);
  const float4 v1 = *(const float4*)(in + (size_t)i * 8 + 4);
  *(uint4*)(out + (size_t)i * 8) =
      make_uint4(pk2bf(v0.x, v0.y), pk2bf(v0.z, v0.w), pk2bf(v1.x, v1.y), pk2bf(v1.z, v1.w));
}

// ------------------------- per-layer edge geometry -------------------------
// only radial changes per layer: 2-byte store into extra[i*32], plus dnb.

__global__ __launch_bounds__(256) void geom_kernel(
    const float* __restrict__ pos_cur,
    const int* __restrict__ rowp, const int* __restrict__ colp,
    float* __restrict__ dnb, ushort* __restrict__ extra) {
  const int i = blockIdx.x * 256 + threadIdx.x;
  if (i >= NE) return;
  const int r = rowp[i], c = colp[i];
  const float4 pr = *(const float4*)(pos_cur + (size_t)r * 4);
  const float4 pc = *(const float4*)(pos_cur + (size_t)c * 4);
  const float dx = pr.x - pc.x, dy = pr.y - pc.y, dz = pr.z - pc.z;
  const float radial = dx * dx + dy * dy + dz * dz;
  const float inv = 1.0f / (sqrtf(radial) + EPSV);
  *(float4*)(dnb + (size_t)i * 4) = make_float4(dx * inv, dy * inv, dz * inv, 0.0f);
  extra[(size_t)i * 32] = f2bf(radial);
}

// ------------------------------- emb_in ------------------------------------

__global__ __launch_bounds__(256) void emb_in_kernel(
    const float* __restrict__ x, const float* __restrict__ W,
    const float* __restrict__ B, float* __restrict__ h, ushort* __restrict__ hbf) {
  __shared__ float xs[NDF * ES];
  const int t = threadIdx.x;
  const int n0 = blockIdx.x * 32;
  {
    const int r = t >> 3;
    const int kq = (t & 7) * 4;
    const float4 v = *(const float4*)(x + (size_t)(n0 + r) * NDF + kq);
    xs[(kq + 0) * ES + r] = v.x;
    xs[(kq + 1) * ES + r] = v.y;
    xs[(kq + 2) * ES + r] = v.z;
    xs[(kq + 3) * ES + r] = v.w;
  }
  __syncthreads();
  const int eg = t & 7, fg = t >> 3;
  float acc[4][4] = {};
  const float* wp = W + fg * 4;
#pragma unroll
  for (int k = 0; k < NDF; ++k) {
    const float4 a = *(const float4*)&xs[k * ES + eg * 4];
    const float4 w = *(const float4*)(wp + (size_t)k * HD);
    fma44(acc, a, w);
  }
  const float4 bv = *(const float4*)(B + fg * 4);
  const float bb[4] = {bv.x, bv.y, bv.z, bv.w};
#pragma unroll
  for (int i = 0; i < 4; ++i) {
    const float4 o = make_float4(acc[i][0] + bb[0], acc[i][1] + bb[1],
                                 acc[i][2] + bb[2], acc[i][3] + bb[3]);
    *(float4*)(h + (size_t)(n0 + eg * 4 + i) * HD + fg * 4) = o;
    *(uint2*)(hbf + (size_t)(n0 + eg * 4 + i) * HD + fg * 4) =
        make_uint2(pk2bf(o.x, o.y), pk2bf(o.z, o.w));
  }
}

// --------------------- transposed MFMA edge kernel -------------------------
// D rows = features (M), cols = edges (N). 64 edges x 128 feats per WG,
// 4 waves (wn, we) in 2x2; per wave 64 feats x 32 edges = 4(mt) x 2(et).

__global__ __launch_bounds__(256) void edge_mfma_kernel(
    const ushort* __restrict__ hbf, const ushort* __restrict__ extra,
    const int* __restrict__ rowp, const int* __restrict__ colp,
    const float* __restrict__ dnb,
    const ushort* __restrict__ W1p, const float* __restrict__ B1,
    const ushort* __restrict__ W2p, const float* __restrict__ B2,
    const float* __restrict__ AW, const float* __restrict__ AB,
    const ushort* __restrict__ CW1p, const float* __restrict__ CB1,
    const float* __restrict__ CW2,
    ushort* __restrict__ m_bf, float* __restrict__ trans_out) {
  __shared__ ushort mtileT[64 * 128];  // [edge][feat^swz], 16 KB
  __shared__ int ridx[64], cidx[64];
  __shared__ float redbuf[2][64];
  __shared__ float gates[64];

  const int t = threadIdx.x;
  // XCD-chunked swizzle: 4096 blocks, 8 XCDs -> contiguous 512-block chunks
  const int bid = blockIdx.x;
  const int e0 = ((bid & 7) * (NE / 64 / 8) + (bid >> 3)) * 64;
  if (t < 64) {
    ridx[t] = rowp[e0 + t];
    cidx[t] = colp[e0 + t];
  }
  __syncthreads();

  const int w = t >> 6, l = t & 63;
  const int wn = w & 1, we = w >> 1;
  const int g = l >> 4, ln = l & 15;
  const int nb = wn * 64;  // feature base (M)
  const int eb = we * 32;  // edge base (N)

  int je[2], er[2], ec[2], swz[2];
#pragma unroll
  for (int et = 0; et < 2; ++et) {
    je[et] = eb + et * 16 + ln;
    er[et] = ridx[je[et]];
    ec[et] = cidx[je[et]];
    swz[et] = (je[et] & 7) << 3;
  }

  const f4_t zf = {0.0f, 0.0f, 0.0f, 0.0f};
  f4_t acc[4][2];
#pragma unroll
  for (int mt = 0; mt < 4; ++mt)
#pragma unroll
    for (int et = 0; et < 2; ++et) acc[mt][et] = zf;

  // ---- GEMM1: m1T[n][e] = sum_k W1[k][n] * e_in[e][k], K=288
#pragma unroll
  for (int kk = 0; kk < KK1; ++kk) {
    bf8_t aw[4], be[2];
#pragma unroll
    for (int mt = 0; mt < 4; ++mt)
      aw[mt] = *(const bf8_t*)(W1p + ((size_t)(kk * 8 + wn * 4 + mt) * 64 + l) * 8);
#pragma unroll
    for (int et = 0; et < 2; ++et) {
      if (kk < 8) {
        const int idx = (kk < 4) ? er[et] : ec[et];
        be[et] = *(const bf8_t*)(hbf + (size_t)idx * HD + (kk & 3) * 32 + g * 8);
      } else {
        be[et] = *(const bf8_t*)(extra + (size_t)(e0 + je[et]) * 32 + g * 8);
      }
    }
#pragma unroll
    for (int mt = 0; mt < 4; ++mt)
#pragma unroll
      for (int et = 0; et < 2; ++et)
        acc[mt][et] = __builtin_amdgcn_mfma_f32_16x16x32_bf16(aw[mt], be[et], acc[mt][et], 0, 0, 0);
  }

  // m1 = silu(acc + b1) -> LDS (cvt_pk + ds_write_b64)
#pragma unroll
  for (int mt = 0; mt < 4; ++mt) {
    const int n0 = nb + mt * 16 + g * 4;
    const float4 bv = *(const float4*)(B1 + n0);
#pragma unroll
    for (int et = 0; et < 2; ++et) {
      const unsigned lo = pk2bf(silu_f(acc[mt][et][0] + bv.x), silu_f(acc[mt][et][1] + bv.y));
      const unsigned hi = pk2bf(silu_f(acc[mt][et][2] + bv.z), silu_f(acc[mt][et][3] + bv.w));
      *(uint2*)&mtileT[je[et] * HD + (n0 ^ swz[et])] = make_uint2(lo, hi);
    }
  }
  __syncthreads();

  // ---- GEMM2: m2T = W2T @ m1T, K=128 (+ attention gate)
  f4_t acc2[4][2];
#pragma unroll
  for (int mt = 0; mt < 4; ++mt)
#pragma unroll
    for (int et = 0; et < 2; ++et) acc2[mt][et] = zf;
#pragma unroll
  for (int kk = 0; kk < KK2; ++kk) {
    bf8_t aw[4], be[2];
#pragma unroll
    for (int mt = 0; mt < 4; ++mt)
      aw[mt] = *(const bf8_t*)(W2p + ((size_t)(kk * 8 + wn * 4 + mt) * 64 + l) * 8);
    const int nk = kk * 32 + g * 8;
#pragma unroll
    for (int et = 0; et < 2; ++et)
      be[et] = *(const bf8_t*)&mtileT[je[et] * HD + (nk ^ swz[et])];
#pragma unroll
    for (int mt = 0; mt < 4; ++mt)
#pragma unroll
      for (int et = 0; et < 2; ++et)
        acc2[mt][et] = __builtin_amdgcn_mfma_f32_16x16x32_bf16(aw[mt], be[et], acc2[mt][et], 0, 0, 0);
  }

  float m2v[4][2][4];
  {
    float p[2] = {0.0f, 0.0f};
#pragma unroll
    for (int mt = 0; mt < 4; ++mt) {
      const int n0 = nb + mt * 16 + g * 4;
      const float4 bv = *(const float4*)(B2 + n0);
      const float4 av = *(const float4*)(AW + n0);
      const float bb[4] = {bv.x, bv.y, bv.z, bv.w};
      const float aa[4] = {av.x, av.y, av.z, av.w};
#pragma unroll
      for (int et = 0; et < 2; ++et)
#pragma unroll
        for (int r = 0; r < 4; ++r) {
          const float v = silu_f(acc2[mt][et][r] + bb[r]);
          m2v[mt][et][r] = v;
          p[et] = fmaf(v, aa[r], p[et]);
        }
    }
#pragma unroll
    for (int et = 0; et < 2; ++et) {
      p[et] += __shfl_xor(p[et], 16, 64);
      p[et] += __shfl_xor(p[et], 32, 64);
    }
    if (l < 16) {
#pragma unroll
      for (int et = 0; et < 2; ++et) redbuf[wn][eb + et * 16 + l] = p[et];
    }
  }
  __syncthreads();
  if (t < 64) gates[t] = sigmoid_f(redbuf[0][t] + redbuf[1][t] + AB[0]);
  __syncthreads();

  // gated m -> LDS
  {
    float grow[2];
#pragma unroll
    for (int et = 0; et < 2; ++et) grow[et] = gates[je[et]];
#pragma unroll
    for (int mt = 0; mt < 4; ++mt) {
      const int n0 = nb + mt * 16 + g * 4;
#pragma unroll
      for (int et = 0; et < 2; ++et) {
        const unsigned lo = pk2bf(m2v[mt][et][0] * grow[et], m2v[mt][et][1] * grow[et]);
        const unsigned hi = pk2bf(m2v[mt][et][2] * grow[et], m2v[mt][et][3] * grow[et]);
        *(uint2*)&mtileT[je[et] * HD + (n0 ^ swz[et])] = make_uint2(lo, hi);
      }
    }
  }
  __syncthreads();

  // ---- GEMM3: t2T = CW1T @ mT, K=128; coord scalar = tanh(t2 . cw2)
  f4_t acc3[4][2];
#pragma unroll
  for (int mt = 0; mt < 4; ++mt)
#pragma unroll
    for (int et = 0; et < 2; ++et) acc3[mt][et] = zf;
#pragma unroll
  for (int kk = 0; kk < KK2; ++kk) {
    bf8_t aw[4], be[2];
#pragma unroll
    for (int mt = 0; mt < 4; ++mt)
      aw[mt] = *(const bf8_t*)(CW1p + ((size_t)(kk * 8 + wn * 4 + mt) * 64 + l) * 8);
    const int nk = kk * 32 + g * 8;
#pragma unroll
    for (int et = 0; et < 2; ++et)
      be[et] = *(const bf8_t*)&mtileT[je[et] * HD + (nk ^ swz[et])];
#pragma unroll
    for (int mt = 0; mt < 4; ++mt)
#pragma unroll
      for (int et = 0; et < 2; ++et)
        acc3[mt][et] = __builtin_amdgcn_mfma_f32_16x16x32_bf16(aw[mt], be[et], acc3[mt][et], 0, 0, 0);
  }
  {
    float q[2] = {0.0f, 0.0f};
#pragma unroll
    for (int mt = 0; mt < 4; ++mt) {
      const int n0 = nb + mt * 16 + g * 4;
      const float4 bv = *(const float4*)(CB1 + n0);
      const float4 cv = *(const float4*)(CW2 + n0);
      const float bb[4] = {bv.x, bv.y, bv.z, bv.w};
      const float cc[4] = {cv.x, cv.y, cv.z, cv.w};
#pragma unroll
      for (int et = 0; et < 2; ++et)
#pragma unroll
        for (int r = 0; r < 4; ++r)
          q[et] = fmaf(silu_f(acc3[mt][et][r] + bb[r]), cc[r], q[et]);
    }
#pragma unroll
    for (int et = 0; et < 2; ++et) {
      q[et] += __shfl_xor(q[et], 16, 64);
      q[et] += __shfl_xor(q[et], 32, 64);
    }
    if (l < 16) {
#pragma unroll
      for (int et = 0; et < 2; ++et) redbuf[wn][eb + et * 16 + l] = q[et];
    }
  }
  __syncthreads();
  if (t < 64) {
    const float s = tanhf(redbuf[0][t] + redbuf[1][t]);
    const f4_t dn = *(const f4_t*)(dnb + (size_t)(e0 + t) * 4);
    const f4_t tr = dn * s;
    *(f4_t*)(trans_out + (size_t)(e0 + t) * 4) = tr;
  }

  // bulk copy gated-m LDS tile -> global m_bf (de-swizzle, coalesced)
#pragma unroll
  for (int it = 0; it < 4; ++it) {
    const int i = it * 256 + t;
    const int row = i >> 4;
    const int c8 = (i & 15) * 8;
    const uint4 v = *(const uint4*)&mtileT[row * HD + (c8 ^ ((row & 7) << 3))];
    *(uint4*)(m_bf + (size_t)(e0 + row) * HD + c8) = v;
  }
}

// ------------------------ gather (segment sums) ----------------------------
// CSR-ordered m rows: fully sequential stream. One wave per node.

__global__ __launch_bounds__(256) void gather_kernel(
    const ushort* __restrict__ m_bf, const float* __restrict__ trans,
    const int* __restrict__ row_ptr,
    ushort* __restrict__ agg_bf, float* __restrict__ pos_cur) {
  const int t = threadIdx.x;
  const int wave = t >> 6, lane = t & 63;
  const int n = blockIdx.x * 4 + wave;
  const int s = row_ptr[n], e_end = row_ptr[n + 1];
  float a0 = 0.0f, a1 = 0.0f, ta = 0.0f;
  for (int i = s; i < e_end; ++i) {
    const ushort2 v = *(const ushort2*)(m_bf + (size_t)i * HD + lane * 2);
    a0 += bf2f(v.x);
    a1 += bf2f(v.y);
    if (lane < 4) ta += trans[(size_t)i * 4 + lane];
  }
  *(unsigned*)(agg_bf + (size_t)n * HD + lane * 2) = pk2bf(a0, a1);
  if (lane < 3) {
    const int dg = e_end - s;
    pos_cur[(size_t)n * 4 + lane] += ta / (float)(dg > 0 ? dg : 1);
  }
}

// --------------------- transposed MFMA node kernel -------------------------
// 64 nodes x 128 feats per WG; sequential activation reads; f32 residual.

__global__ __launch_bounds__(256) void node_mfma_kernel(
    float* __restrict__ h, const ushort* __restrict__ hbf,
    const ushort* __restrict__ agg_bf,
    const ushort* __restrict__ W1p, const float* __restrict__ B1,
    const ushort* __restrict__ W2p, const float* __restrict__ B2,
    ushort* __restrict__ hbf_out) {
  __shared__ ushort mtileT[64 * 128];
  const int t = threadIdx.x;
  const int n0blk = blockIdx.x * 64;
  const int w = t >> 6, l = t & 63;
  const int wn = w & 1, we = w >> 1;
  const int g = l >> 4, ln = l & 15;
  const int nb = wn * 64;
  const int eb = we * 32;

  int jn[2], swz[2];
#pragma unroll
  for (int et = 0; et < 2; ++et) {
    jn[et] = eb + et * 16 + ln;
    swz[et] = (jn[et] & 7) << 3;
  }

  const f4_t zf = {0.0f, 0.0f, 0.0f, 0.0f};
  f4_t acc[4][2];
#pragma unroll
  for (int mt = 0; mt < 4; ++mt)
#pragma unroll
    for (int et = 0; et < 2; ++et) acc[mt][et] = zf;

  // GEMM1: K=256 ([h|agg])
#pragma unroll
  for (int kk = 0; kk < KKN1; ++kk) {
    bf8_t aw[4], be[2];
#pragma unroll
    for (int mt = 0; mt < 4; ++mt)
      aw[mt] = *(const bf8_t*)(W1p + ((size_t)(kk * 8 + wn * 4 + mt) * 64 + l) * 8);
#pragma unroll
    for (int et = 0; et < 2; ++et) {
      const size_t base = (size_t)(n0blk + jn[et]) * HD + (kk & 3) * 32 + g * 8;
      be[et] = (kk < 4) ? *(const bf8_t*)(hbf + base) : *(const bf8_t*)(agg_bf + base);
    }
#pragma unroll
    for (int mt = 0; mt < 4; ++mt)
#pragma unroll
      for (int et = 0; et < 2; ++et)
        acc[mt][et] = __builtin_amdgcn_mfma_f32_16x16x32_bf16(aw[mt], be[et], acc[mt][et], 0, 0, 0);
  }
#pragma unroll
  for (int mt = 0; mt < 4; ++mt) {
    const int n0 = nb + mt * 16 + g * 4;
    const float4 bv = *(const float4*)(B1 + n0);
#pragma unroll
    for (int et = 0; et < 2; ++et) {
      const unsigned lo = pk2bf(silu_f(acc[mt][et][0] + bv.x), silu_f(acc[mt][et][1] + bv.y));
      const unsigned hi = pk2bf(silu_f(acc[mt][et][2] + bv.z), silu_f(acc[mt][et][3] + bv.w));
      *(uint2*)&mtileT[jn[et] * HD + (n0 ^ swz[et])] = make_uint2(lo, hi);
    }
  }
  __syncthreads();

  // GEMM2: K=128; h += out + b2
  f4_t acc2[4][2];
#pragma unroll
  for (int mt = 0; mt < 4; ++mt)
#pragma unroll
    for (int et = 0; et < 2; ++et) acc2[mt][et] = zf;
#pragma unroll
  for (int kk = 0; kk < KK2; ++kk) {
    bf8_t aw[4], be[2];
#pragma unroll
    for (int mt = 0; mt < 4; ++mt)
      aw[mt] = *(const bf8_t*)(W2p + ((size_t)(kk * 8 + wn * 4 + mt) * 64 + l) * 8);
    const int nk = kk * 32 + g * 8;
#pragma unroll
    for (int et = 0; et < 2; ++et)
      be[et] = *(const bf8_t*)&mtileT[jn[et] * HD + (nk ^ swz[et])];
#pragma unroll
    for (int mt = 0; mt < 4; ++mt)
#pragma unroll
      for (int et = 0; et < 2; ++et)
        acc2[mt][et] = __builtin_amdgcn_mfma_f32_16x16x32_bf16(aw[mt], be[et], acc2[mt][et], 0, 0, 0);
  }
#pragma unroll
  for (int mt = 0; mt < 4; ++mt) {
    const int n0 = nb + mt * 16 + g * 4;
    const float4 bv = *(const float4*)(B2 + n0);
#pragma unroll
    for (int et = 0; et < 2; ++et) {
      float* hp = h + (size_t)(n0blk + jn[et]) * HD + n0;
      const float4 old = *(const float4*)hp;
      float4 o;
      o.x = old.x + acc2[mt][et][0] + bv.x;
      o.y = old.y + acc2[mt][et][1] + bv.y;
      o.z = old.z + acc2[mt][et][2] + bv.z;
      o.w = old.w + acc2[mt][et][3] + bv.w;
      *(float4*)hp = o;
      *(uint2*)(hbf_out + (size_t)(n0blk + jn[et]) * HD + n0) =
          make_uint2(pk2bf(o.x, o.y), pk2bf(o.z, o.w));
    }
  }
}

// ------------------------- generic MFMA head GEMM --------------------------

__global__ __launch_bounds__(256) void gemm_head_kernel(
    const ushort* __restrict__ A, const ushort* __restrict__ Wp,
    const float* __restrict__ bias, ushort* __restrict__ out,
    int lda, int KK, int NTG, int ldo, int col_off) {
  const int t = threadIdx.x;
  const int rb = blockIdx.x * 64;
  const int cb = blockIdx.y * 128;
  const int w = t >> 6, l = t & 63;
  const int wr = w >> 1, wc = w & 1;
  const int g = l >> 4, ln = l & 15;
  const int row0 = wr * 32;
  int rowA[2];
#pragma unroll
  for (int mt = 0; mt < 2; ++mt) rowA[mt] = row0 + mt * 16 + ln;

  const f4_t zf = {0.0f, 0.0f, 0.0f, 0.0f};
  f4_t acc[2][4];
#pragma unroll
  for (int mt = 0; mt < 2; ++mt)
#pragma unroll
    for (int nt = 0; nt < 4; ++nt) acc[mt][nt] = zf;

  const int ntg0 = (cb >> 4) + wc * 4;
  for (int kk = 0; kk < KK; ++kk) {
    bf8_t a[2], b[4];
#pragma unroll
    for (int mt = 0; mt < 2; ++mt)
      a[mt] = *(const bf8_t*)(A + (size_t)(rb + rowA[mt]) * lda + kk * 32 + g * 8);
#pragma unroll
    for (int nt = 0; nt < 4; ++nt)
      b[nt] = *(const bf8_t*)(Wp + ((size_t)(kk * NTG + ntg0 + nt) * 64 + l) * 8);
#pragma unroll
    for (int mt = 0; mt < 2; ++mt)
#pragma unroll
      for (int nt = 0; nt < 4; ++nt)
        acc[mt][nt] = __builtin_amdgcn_mfma_f32_16x16x32_bf16(a[mt], b[nt], acc[mt][nt], 0, 0, 0);
  }
  {
    float bn[4];
#pragma unroll
    for (int nt = 0; nt < 4; ++nt) bn[nt] = bias[cb + wc * 64 + nt * 16 + ln];
#pragma unroll
    for (int mt = 0; mt < 2; ++mt)
#pragma unroll
      for (int nt = 0; nt < 4; ++nt) {
        const int col = cb + wc * 64 + nt * 16 + ln;
#pragma unroll
        for (int r = 0; r < 4; ++r) {
          const int row = row0 + mt * 16 + g * 4 + r;
          const float v = fmaxf(acc[mt][nt][r] + bn[nt], 0.0f);
          out[(size_t)(rb + row) * ldo + col_off + col] = f2bf(v);
        }
      }
  }
}

// ------------------------------ heads --------------------------------------

__global__ __launch_bounds__(128) void pool_kernel(
    const float* __restrict__ h, const float* __restrict__ W,
    const float* __restrict__ B, ushort* __restrict__ c_in) {
  __shared__ float mh[HD];
  const int g = blockIdx.x, t = threadIdx.x;
  float s = 0.0f;
#pragma unroll 4
  for (int n = 0; n < 32; ++n) s += h[((size_t)g * 32 + n) * HD + t];
  mh[t] = s * (1.0f / 32.0f);
  __syncthreads();
  float acc = B[t];
#pragma unroll 4
  for (int k = 0; k < HD; ++k) acc = fmaf(mh[k], W[(size_t)k * HD + t], acc);
  c_in[(size_t)g * (HD + PHD) + t] = f2bf(acc);
}

__global__ __launch_bounds__(256) void logits_kernel(
    const ushort* __restrict__ c, const float* __restrict__ w2,
    const float* __restrict__ b2, float* __restrict__ out) {
  const int t = threadIdx.x;
  const int wave = t >> 6, lane = t & 63;
  const int r = blockIdx.x * 4 + wave;
  const ushort* cp = c + (size_t)r * CHD + lane * 8;
  const float* wp = w2 + lane * 8;
  float s = 0.0f;
#pragma unroll
  for (int j = 0; j < 8; ++j) s = fmaf(bf2f(cp[j]), wp[j], s);
#pragma unroll
  for (int off = 32; off > 0; off >>= 1) s += __shfl_down(s, off, 64);
  if (lane == 0) {
    out[r] = s + b2[0];
    out[NB + r] = 0.0f;
  }
}

// ------------------------------ launch -------------------------------------

extern "C" void kernel_launch(void* const* d_in, const int* in_sizes, int n_in,
                              void* d_out, int out_size, void* d_ws, size_t ws_size,
                              hipStream_t stream) {
  const float* x          = (const float*)d_in[0];
  const float* pos        = (const float*)d_in[1];
  const float* edge_attr  = (const float*)d_in[2];
  const float* pe         = (const float*)d_in[3];
  const int*   edge_index = (const int*)d_in[4];
  const float* emb_in_w   = (const float*)d_in[6];
  const float* emb_in_b   = (const float*)d_in[7];
  const float* emb_out_w  = (const float*)d_in[8];
  const float* emb_out_b  = (const float*)d_in[9];
  const float* edge_w1    = (const float*)d_in[10];
  const float* edge_b1    = (const float*)d_in[11];
  const float* edge_w2    = (const float*)d_in[12];
  const float* edge_b2    = (const float*)d_in[13];
  const float* att_w      = (const float*)d_in[14];
  const float* att_b      = (const float*)d_in[15];
  const float* coord_w1   = (const float*)d_in[16];
  const float* coord_b1   = (const float*)d_in[17];
  const float* coord_w2   = (const float*)d_in[18];
  const float* node_w1    = (const float*)d_in[19];
  const float* node_b1    = (const float*)d_in[20];
  const float* node_w2    = (const float*)d_in[21];
  const float* node_b2    = (const float*)d_in[22];
  const float* prot_w     = (const float*)d_in[23];
  const float* prot_b     = (const float*)d_in[24];
  const float* comb_w1    = (const float*)d_in[25];
  const float* comb_b1    = (const float*)d_in[26];
  const float* comb_w2    = (const float*)d_in[27];
  const float* comb_b2    = (const float*)d_in[28];
  float* out = (float*)d_out;
  (void)in_sizes; (void)n_in; (void)out_size; (void)ws_size;

  char* ws = (char*)d_ws;
  size_t off = 0;
  auto carve = [&](size_t bytes) -> void* {
    void* p = ws + off;
    off += (bytes + 255) & ~(size_t)255;
    return p;
  };
  float*  h       = (float*)carve((size_t)NN * HD * 4);
  ushort* h_bf    = (ushort*)carve((size_t)NN * HD * 2);
  ushort* agg_bf  = (ushort*)carve((size_t)NN * HD * 2);
  ushort* m_bf    = (ushort*)carve((size_t)NE * HD * 2);
  float*  trans   = (float*)carve((size_t)NE * 4 * 4);
  float*  dnb     = (float*)carve((size_t)NE * 4 * 4);
  ushort* extra   = (ushort*)carve((size_t)NE * 32 * 2);
  float*  pos_cur = (float*)carve((size_t)NN * 4 * 4);
  ushort* pe_bf   = (ushort*)carve((size_t)NB * PED * 2);
  ushort* c_in    = (ushort*)carve((size_t)NB * (HD + PHD) * 2);
  ushort* c1      = (ushort*)carve((size_t)NB * CHD * 2);
  const size_t sW1p  = (size_t)KK1 * 8 * 64 * 8;
  const size_t sW2p  = (size_t)KK2 * 8 * 64 * 8;
  const size_t sNW1p = (size_t)KKN1 * 8 * 64 * 8;
  const size_t sPWp  = (size_t)KKP * 32 * 64 * 8;
  const size_t sCWp  = (size_t)KKC * 32 * 64 * 8;
  ushort* W1p     = (ushort*)carve(sW1p * NL * 2);
  ushort* W2p     = (ushort*)carve(sW2p * NL * 2);
  ushort* CW1p    = (ushort*)carve(sW2p * NL * 2);
  ushort* NW1p    = (ushort*)carve(sNW1p * NL * 2);
  ushort* NW2p    = (ushort*)carve(sW2p * NL * 2);
  ushort* PWp     = (ushort*)carve(sPWp * 2);
  ushort* CWp     = (ushort*)carve(sCWp * 2);
  int* deg        = (int*)carve((size_t)NN * 4);
  int* row_ptr    = (int*)carve((size_t)(NN + 1) * 4);
  int* fill_pos   = (int*)carve((size_t)NN * 4);
  int* edge_ids   = (int*)carve((size_t)NE * 4);
  int* rowp       = (int*)carve((size_t)NE * 4);
  int* colp       = (int*)carve((size_t)NE * 4);
  int* cbase      = (int*)carve((size_t)256 * 4);

  hipMemsetAsync(deg, 0, (size_t)NN * 4, stream);
  hipMemsetAsync(fill_pos, 0, (size_t)NN * 4, stream);

  pos_copy_kernel<<<NN / 256, 256, 0, stream>>>(pos, pos_cur);
  hist_kernel<<<NE / 256, 256, 0, stream>>>(edge_index, deg);
  scan1_kernel<<<1, 256, 0, stream>>>(deg, cbase);
  scan2_kernel<<<NN / 256, 256, 0, stream>>>(deg, cbase, row_ptr);
  fill_kernel<<<NE / 256, 256, 0, stream>>>(edge_index, row_ptr, fill_pos, edge_ids);
  perm_kernel<<<NE / 256, 256, 0, stream>>>(edge_index, edge_ids, edge_attr,
                                            rowp, colp, extra);

  packw_kernel<<<dim3(18, NL), 256, 0, stream>>>(edge_w1, W1p, 265, HD, KK1,
                                                 (size_t)265 * HD, sW1p);
  packw_kernel<<<dim3(8, NL), 256, 0, stream>>>(edge_w2, W2p, HD, HD, KK2,
                                                (size_t)HD * HD, sW2p);
  packw_kernel<<<dim3(8, NL), 256, 0, stream>>>(coord_w1, CW1p, HD, HD, KK2,
                                                (size_t)HD * HD, sW2p);
  packw_kernel<<<dim3(16, NL), 256, 0, stream>>>(node_w1, NW1p, 2 * HD, HD, KKN1,
                                                 (size_t)2 * HD * HD, sNW1p);
  packw_kernel<<<dim3(8, NL), 256, 0, stream>>>(node_w2, NW2p, HD, HD, KK2,
                                                (size_t)HD * HD, sW2p);
  packw_kernel<<<dim3(320, 1), 256, 0, stream>>>(prot_w, PWp, PED, PHD, KKP, 0, 0);
  packw_kernel<<<dim3(160, 1), 256, 0, stream>>>(comb_w1, CWp, HD + PHD, CHD, KKC, 0, 0);

  cvt_bf_kernel<<<NB * PED / (256 * 8), 256, 0, stream>>>(pe, pe_bf, NB * PED);

  emb_in_kernel<<<NN / 32, 256, 0, stream>>>(x, emb_in_w, emb_in_b, h, h_bf);

  for (int l = 0; l < NL; ++l) {
    geom_kernel<<<NE / 256, 256, 0, stream>>>(pos_cur, rowp, colp, dnb, extra);
    edge_mfma_kernel<<<NE / 64, 256, 0, stream>>>(
        h_bf, extra, rowp, colp, dnb,
        W1p + (size_t)l * sW1p, edge_b1 + (size_t)l * HD,
        W2p + (size_t)l * sW2p, edge_b2 + (size_t)l * HD,
        att_w + (size_t)l * HD, att_b + l,
        CW1p + (size_t)l * sW2p, coord_b1 + (size_t)l * HD,
        coord_w2 + (size_t)l * HD,
        m_bf, trans);
    gather_kernel<<<NN / 4, 256, 0, stream>>>(m_bf, trans, row_ptr, agg_bf, pos_cur);
    node_mfma_kernel<<<NN / 64, 256, 0, stream>>>(
        h, h_bf, agg_bf,
        NW1p + (size_t)l * sNW1p, node_b1 + (size_t)l * HD,
        NW2p + (size_t)l * sW2p, node_b2 + (size_t)l * HD, h_bf);
  }

  pool_kernel<<<NB, 128, 0, stream>>>(h, emb_out_w, emb_out_b, c_in);
  gemm_head_kernel<<<dim3(NB / 64, PHD / 128), 256, 0, stream>>>(
      pe_bf, PWp, prot_b, c_in, PED, KKP, PHD / 16, HD + PHD, HD);
  gemm_head_kernel<<<dim3(NB / 64, CHD / 128), 256, 0, stream>>>(
      c_in, CWp, comb_b1, c1, HD + PHD, KKC, CHD / 16, CHD, 0);
  logits_kernel<<<NB / 4, 256, 0, stream>>>(c1, comb_w2, comb_b2, out);
}